// Round 1
// baseline (413.065 us; speedup 1.0000x reference)
//
#include <hip/hip_runtime.h>
#include <math.h>

#define SRATE   16000
#define FLEN    400
#define STEP    160
#define NFFT    512
#define NBINS   257
#define NFILT   26
#define NUMCEP  13
#define BATCH   64
#define TLEN    320000
#define NFRAMES 1999
#define EPSF    1.1920929e-07f
#define PI_F    3.14159265358979323846f

// ---------------------------------------------------------------------------
// Setup kernel: compute mel filterbank bin edges in f64 (must match numpy's
// floor exactly) into d_ws, and write the nframes output (as f32 — d_out is
// read back as one flat f32 buffer, outputs concatenated).
// ---------------------------------------------------------------------------
__global__ void mfcc_setup_kernel(const int* __restrict__ lengths,
                                  int* __restrict__ bins_out,
                                  float* __restrict__ out_nframes) {
    int tid = threadIdx.x;
    if (tid < 28) {
        double M    = 2595.0 * log10(1.0 + 8000.0 / 700.0);
        double step = M / 27.0;
        double mel  = (tid == 27) ? M : (double)tid * step;   // numpy linspace
        double hz   = 700.0 * (pow(10.0, mel / 2595.0) - 1.0);
        bins_out[tid] = (int)floor((double)(NFFT + 1) * hz / (double)SRATE);
    }
    if (tid < BATCH) {
        int len = lengths[tid];
        int nf  = (len <= FLEN) ? 1 : 1 + (len - FLEN + STEP - 1) / STEP;
        out_nframes[tid] = (float)nf;
    }
}

// ---------------------------------------------------------------------------
// Main kernel: one wave (64 lanes) per frame, 4 frames per 256-thread block.
// ---------------------------------------------------------------------------
__launch_bounds__(256)
__global__ void mfcc_kernel(const float* __restrict__ sig,
                            const int*   __restrict__ lengths,
                            const int*   __restrict__ bins_g,
                            float*       __restrict__ out) {
    __shared__ float xr[4][NFFT];
    __shared__ float xi[4][NFFT];
    __shared__ float twr[256], twim[256];
    __shared__ float dctm[NUMCEP][NFILT];
    __shared__ float featS[4][NFILT];
    __shared__ int   binsS[NFILT + 2];

    const int tid  = threadIdx.x;
    const int lane = tid & 63;
    const int w    = tid >> 6;

    // ---- per-block precompute (twiddles, DCT matrix, bins) ----
    {
        float ang = -2.0f * PI_F * (float)tid / (float)NFFT;
        float sn, cs;
        sincosf(ang, &sn, &cs);
        twr[tid]  = cs;
        twim[tid] = sn;
    }
    for (int t = tid; t < NUMCEP * NFILT; t += 256) {
        int k = t / NFILT, j = t - k * NFILT;
        float v = cosf(PI_F * (float)((2 * j + 1) * k) / (2.0f * (float)NFILT));
        v *= (k == 0) ? rsqrtf((float)NFILT) : sqrtf(2.0f / (float)NFILT);
        dctm[k][j] = v;
    }
    if (tid < NFILT + 2) binsS[tid] = bins_g[tid];
    __syncthreads();

    // ---- frame identity ----
    const int gf = blockIdx.x * 4 + w;
    const int b  = gf / NFRAMES;
    const int f  = gf - b * NFRAMES;
    const int len = lengths[b];
    const float* s = sig + (long)b * TLEN;
    const int base = f * STEP;

    // ---- load + pre-emphasis + length mask, bit-reversed scatter ----
    for (int i = lane; i < NFFT; i += 64) {
        float v = 0.0f;
        int t = base + i;
        if (i < FLEN && t < len) {          // t < len <= TLEN-1 -> safe loads
            float st = s[t];
            v = (t == 0) ? st : fmaf(-0.97f, s[t - 1], st);
        }
        int r = (int)(__brev((unsigned)i) >> 23);   // 9-bit bit-reverse
        xr[w][r] = v;
        xi[w][r] = 0.0f;
    }
    __syncthreads();

    // ---- 512-pt radix-2 DIT FFT (input bit-reversed, output natural) ----
    for (int st = 0; st < 9; ++st) {
        int half = 1 << st;
        #pragma unroll
        for (int it = 0; it < 4; ++it) {
            int bf  = lane + (it << 6);          // butterfly 0..255
            int pos = bf & (half - 1);
            int grp = bf >> st;
            int i0  = (grp << (st + 1)) + pos;
            int i1  = i0 + half;
            int ti  = pos << (8 - st);
            float c  = twr[ti], sn = twim[ti];
            float ar = xr[w][i1], ai = xi[w][i1];
            float tr = ar * c - ai * sn;
            float tq = ar * sn + ai * c;
            float br = xr[w][i0], bi = xi[w][i0];
            xr[w][i0] = br + tr;  xi[w][i0] = bi + tq;
            xr[w][i1] = br - tr;  xi[w][i1] = bi - tq;
        }
        __syncthreads();
    }

    // ---- power spectrum (into xi) + energy reduction ----
    float ep = 0.0f;
    for (int k = lane; k < NBINS; k += 64) {
        float re = xr[w][k], im = xi[w][k];
        float p = (re * re + im * im) * (1.0f / (float)NFFT);
        xi[w][k] = p;
        ep += p;
    }
    #pragma unroll
    for (int off = 32; off >= 1; off >>= 1)
        ep += __shfl_xor(ep, off);
    const float energy = ep + EPSF;
    __syncthreads();

    // ---- mel filterbank + log ----
    if (lane < NFILT) {
        int b0 = binsS[lane], b1 = binsS[lane + 1], b2 = binsS[lane + 2];
        float acc = 0.0f;
        float inv01 = 1.0f / (float)(b1 - b0);
        for (int i = b0; i < b1; ++i)
            acc += xi[w][i] * (float)(i - b0) * inv01;
        float inv12 = 1.0f / (float)(b2 - b1);
        for (int i = b1; i < b2; ++i)
            acc += xi[w][i] * (float)(b2 - i) * inv12;
        featS[w][lane] = logf(acc + EPSF);
    }
    __syncthreads();

    // ---- DCT + lifter + frame mask + write ----
    const int nf = (len <= FLEN) ? 1 : 1 + (len - FLEN + STEP - 1) / STEP;
    if (lane < NUMCEP) {
        float acc = 0.0f;
        #pragma unroll
        for (int j = 0; j < NFILT; ++j)
            acc += featS[w][j] * dctm[lane][j];
        float lift = 1.0f + 11.0f * sinf(PI_F * (float)lane / 22.0f);
        float val = acc * lift;
        if (lane == 0) val = logf(energy);
        if (f >= nf)   val = 0.0f;
        out[((long)b * NFRAMES + f) * NUMCEP + lane] = val;
    }
}

extern "C" void kernel_launch(void* const* d_in, const int* in_sizes, int n_in,
                              void* d_out, int out_size, void* d_ws, size_t ws_size,
                              hipStream_t stream) {
    const float* sig     = (const float*)d_in[0];
    const int*   lengths = (const int*)d_in[1];
    float* out  = (float*)d_out;
    int*   bins = (int*)d_ws;

    mfcc_setup_kernel<<<1, 64, 0, stream>>>(lengths, bins,
                                            out + (size_t)BATCH * NFRAMES * NUMCEP);

    const int total_frames = BATCH * NFRAMES;     // 127936, divisible by 4
    mfcc_kernel<<<total_frames / 4, 256, 0, stream>>>(sig, lengths, bins, out);
}

// Round 2
// 234.409 us; speedup vs baseline: 1.7622x; 1.7622x over previous
//
#include <hip/hip_runtime.h>
#include <math.h>

#define SRATE   16000
#define FLEN    400
#define STEP    160
#define NFFT    512
#define NBINS   257
#define NFILT   26
#define NUMCEP  13
#define BATCH   64
#define TLEN    320000
#define NFRAMES 1999
#define NPAIRS  1000          // frame pairs per batch element (2*g, 2*g+1)
#define EPSF    1.1920929e-07f
#define PI_F    3.14159265358979323846f

// XOR swizzle: fold bit5 into bits{0,2}, bit6 into bits{1,3}. Rank-5 bank
// coverage (2 lanes/bank = free) for every FFT stage access pattern.
__device__ __forceinline__ int SW(int i) {
    return i ^ (((i >> 5) & 1) * 5) ^ (((i >> 6) & 1) * 10);
}
// Twiddle table swizzle (256 entries): additionally fold bit7 into bit4.
__device__ __forceinline__ int SWT(int i) {
    return i ^ (((i >> 5) & 1) * 5) ^ (((i >> 6) & 1) * 10) ^ (((i >> 7) & 1) * 16);
}

// ---------------------------------------------------------------------------
// Setup: mel bin edges in f64 (match numpy floor exactly) + nframes output.
// ---------------------------------------------------------------------------
__global__ void mfcc_setup_kernel(const int* __restrict__ lengths,
                                  int* __restrict__ bins_out,
                                  float* __restrict__ out_nframes) {
    int tid = threadIdx.x;
    if (tid < 28) {
        double M    = 2595.0 * log10(1.0 + 8000.0 / 700.0);
        double step = M / 27.0;
        double mel  = (tid == 27) ? M : (double)tid * step;
        double hz   = 700.0 * (pow(10.0, mel / 2595.0) - 1.0);
        bins_out[tid] = (int)floor((double)(NFFT + 1) * hz / (double)SRATE);
    }
    if (tid < BATCH) {
        int len = lengths[tid];
        int nf  = (len <= FLEN) ? 1 : 1 + (len - FLEN + STEP - 1) / STEP;
        out_nframes[tid] = (float)nf;
    }
}

// ---------------------------------------------------------------------------
// Main kernel: one wave per FRAME PAIR (two real frames packed into one
// complex 512-pt FFT). 4 pairs per 256-thread block. Wave-synchronous LDS
// (no __syncthreads inside the FFT).
// ---------------------------------------------------------------------------
__launch_bounds__(256)
__global__ void mfcc_kernel(const float* __restrict__ sig,
                            const int*   __restrict__ lengths,
                            const int*   __restrict__ bins_g,
                            float*       __restrict__ out) {
    __shared__ float xr[4][NFFT];
    __shared__ float xi[4][NFFT];
    __shared__ float twr[256], twi[256];
    __shared__ float dctm[NUMCEP][NFILT];
    __shared__ float feat0[4][NFILT], feat1[4][NFILT];
    __shared__ int   binsS[NFILT + 2];

    const int tid  = threadIdx.x;
    const int lane = tid & 63;
    const int w    = tid >> 6;

    // ---- per-block constants ----
    {
        float ang = -2.0f * PI_F * (float)tid / (float)NFFT;
        float sn, cs;
        sincosf(ang, &sn, &cs);
        twr[SWT(tid)] = cs;
        twi[SWT(tid)] = sn;
    }
    for (int t = tid; t < NUMCEP * NFILT; t += 256) {
        int k = t / NFILT, j = t - k * NFILT;
        float v = cosf(PI_F * (float)((2 * j + 1) * k) / (2.0f * (float)NFILT));
        v *= (k == 0) ? rsqrtf((float)NFILT) : sqrtf(2.0f / (float)NFILT);
        dctm[k][j] = v;
    }
    if (tid < NFILT + 2) binsS[tid] = bins_g[tid];
    __syncthreads();

    // ---- pair identity ----
    const int gp = blockIdx.x * 4 + w;          // 0 .. 63999
    const int b  = gp / NPAIRS;
    const int g  = gp - b * NPAIRS;
    const int f0 = 2 * g;
    const int f1 = f0 + 1;                       // may be NFRAMES (invalid)
    const int len = lengths[b];
    const float* s = sig + (long)b * TLEN;
    const int base = f0 * STEP;

    // ---- load both frames (pre-emphasis + length mask), bit-rev scatter ----
    for (int i = lane; i < NFFT; i += 64) {
        float v0 = 0.0f, v1 = 0.0f;
        if (i < FLEN) {
            int t0 = base + i;
            if (t0 < len) {
                float st0 = s[t0];
                v0 = (t0 == 0) ? st0 : fmaf(-0.97f, s[t0 - 1], st0);
            }
            int t1 = t0 + STEP;                  // >= 160, never 0
            if (t1 < len)
                v1 = fmaf(-0.97f, s[t1 - 1], s[t1]);
        }
        int r = (int)(__brev((unsigned)i) >> 23);
        int rs = SW(r);
        xr[w][rs] = v0;
        xi[w][rs] = v1;
    }
    __builtin_amdgcn_wave_barrier();

    // ---- 512-pt radix-2 DIT FFT, wave-private, swizzled LDS ----
    for (int st = 0; st < 9; ++st) {
        int half = 1 << st;
        #pragma unroll
        for (int it = 0; it < 4; ++it) {
            int bf  = lane + (it << 6);
            int pos = bf & (half - 1);
            int grp = bf >> st;
            int i0  = (grp << (st + 1)) + pos;
            int i1  = i0 + half;
            int ti  = SWT(pos << (8 - st));
            int s0  = SW(i0), s1 = SW(i1);
            float c  = twr[ti], sn = twi[ti];
            float ar = xr[w][s1], ai = xi[w][s1];
            float tr = ar * c - ai * sn;
            float tq = ar * sn + ai * c;
            float br = xr[w][s0], bi = xi[w][s0];
            xr[w][s0] = br + tr;  xi[w][s0] = bi + tq;
            xr[w][s1] = br - tr;  xi[w][s1] = bi - tq;
        }
        __builtin_amdgcn_wave_barrier();
    }

    // ---- unpack two real spectra + power + energy ----
    // X0[k] = (Z[k]+conj(Z[-k]))/2 ; X1[k] = (Z[k]-conj(Z[-k]))/(2j)
    float ep0 = 0.0f, ep1 = 0.0f;
    const float inv = 1.0f / (4.0f * (float)NFFT);
    #pragma unroll
    for (int ii = 0; ii < 5; ++ii) {
        int k = lane + (ii << 6);
        if (k <= 256) {
            int m  = (NFFT - k) & (NFFT - 1);
            int sk = SW(k), sm = SW(m);
            float zrk = xr[w][sk], zik = xi[w][sk];
            float zrm = xr[w][sm], zim = xi[w][sm];
            float ar = zrk + zrm, ai = zik - zim;     // 2*X0
            float br2 = zik + zim, bi2 = zrk - zrm;   // 2j*X1 -> |.| same
            float p0 = (ar * ar + ai * ai) * inv;
            float p1 = (br2 * br2 + bi2 * bi2) * inv;
            xr[w][sk] = p0;                            // pspec frame0
            xi[w][sk] = p1;                            // pspec frame1
            ep0 += p0;
            ep1 += p1;
        }
    }
    __builtin_amdgcn_wave_barrier();

    #pragma unroll
    for (int off = 32; off >= 1; off >>= 1) {
        ep0 += __shfl_xor(ep0, off);
        ep1 += __shfl_xor(ep1, off);
    }

    // ---- mel filterbank: lanes 0..25 -> frame0, lanes 32..57 -> frame1 ----
    {
        int j = lane & 31;
        bool hi = (lane >= 32);
        const float* ps = hi ? xi[w] : xr[w];
        if (j < NFILT) {
            int b0 = binsS[j], b1 = binsS[j + 1], b2 = binsS[j + 2];
            float acc = 0.0f;
            float inv01 = 1.0f / (float)(b1 - b0);
            for (int i = b0; i < b1; ++i)
                acc += ps[SW(i)] * (float)(i - b0) * inv01;
            float inv12 = 1.0f / (float)(b2 - b1);
            for (int i = b1; i < b2; ++i)
                acc += ps[SW(i)] * (float)(b2 - i) * inv12;
            float fv = logf(acc + EPSF);
            if (hi) feat1[w][j] = fv; else feat0[w][j] = fv;
        }
    }
    __builtin_amdgcn_wave_barrier();

    // ---- DCT + lifter + mask + store: lanes 0..12 / 32..44 ----
    const int nf = (len <= FLEN) ? 1 : 1 + (len - FLEN + STEP - 1) / STEP;
    {
        int k = lane & 31;
        bool hi = (lane >= 32);
        if (k < NUMCEP) {
            const float* ft = hi ? feat1[w] : feat0[w];
            float acc = 0.0f;
            #pragma unroll
            for (int j = 0; j < NFILT; ++j)
                acc += ft[j] * dctm[k][j];
            float lift = 1.0f + 11.0f * sinf(PI_F * (float)k / 22.0f);
            float val = acc * lift;
            if (k == 0) val = logf((hi ? ep1 : ep0) + EPSF);
            int f = hi ? f1 : f0;
            if (f < NFRAMES) {
                if (f >= nf) val = 0.0f;
                out[((long)b * NFRAMES + f) * NUMCEP + k] = val;
            }
        }
    }
}

extern "C" void kernel_launch(void* const* d_in, const int* in_sizes, int n_in,
                              void* d_out, int out_size, void* d_ws, size_t ws_size,
                              hipStream_t stream) {
    const float* sig     = (const float*)d_in[0];
    const int*   lengths = (const int*)d_in[1];
    float* out  = (float*)d_out;
    int*   bins = (int*)d_ws;

    mfcc_setup_kernel<<<1, 64, 0, stream>>>(lengths, bins,
                                            out + (size_t)BATCH * NFRAMES * NUMCEP);

    const int total_pairs = BATCH * NPAIRS;      // 64000, divisible by 4
    mfcc_kernel<<<total_pairs / 4, 256, 0, stream>>>(sig, lengths, bins, out);
}

// Round 3
// 81.792 us; speedup vs baseline: 5.0502x; 2.8659x over previous
//
#include <hip/hip_runtime.h>
#include <math.h>

#define SRATE   16000
#define FLEN    400
#define STEP    160
#define NFFT    512
#define NBINS   257
#define NFILT   26
#define NUMCEP  13
#define BATCH   64
#define TLEN    320000
#define NFRAMES 1999
#define NPAIRS  1000
#define EPSF    1.1920929e-07f
#define PI_F    3.14159265358979323846f

// ---------------------------------------------------------------------------
// Setup: mel bin edges in f64 (match numpy floor exactly) + nframes output.
// ---------------------------------------------------------------------------
__global__ void mfcc_setup_kernel(const int* __restrict__ lengths,
                                  int* __restrict__ bins_out,
                                  float* __restrict__ out_nframes) {
    int tid = threadIdx.x;
    if (tid < 28) {
        double M    = 2595.0 * log10(1.0 + 8000.0 / 700.0);
        double step = M / 27.0;
        double mel  = (tid == 27) ? M : (double)tid * step;
        double hz   = 700.0 * (pow(10.0, mel / 2595.0) - 1.0);
        bins_out[tid] = (int)floor((double)(NFFT + 1) * hz / (double)SRATE);
    }
    if (tid < BATCH) {
        int len = lengths[tid];
        int nf  = (len <= FLEN) ? 1 : 1 + (len - FLEN + STEP - 1) / STEP;
        out_nframes[tid] = (float)nf;
    }
}

// ---------------------------------------------------------------------------
// Main kernel: one wave per frame pair; all-register 512-pt FFT
// (8 complex pts/lane, shfl_xor cross-lane stages, in-register high stages).
// ---------------------------------------------------------------------------
__launch_bounds__(256)
__global__ void mfcc_kernel(const float* __restrict__ sig,
                            const int*   __restrict__ lengths,
                            const int*   __restrict__ bins_g,
                            float*       __restrict__ out) {
    __shared__ float ps0[4][NBINS + 3];
    __shared__ float ps1[4][NBINS + 3];
    __shared__ float feat0[4][28], feat1[4][28];
    __shared__ float dctm[NUMCEP][NFILT];
    __shared__ int   binsS[NFILT + 2];

    const int tid  = threadIdx.x;
    const int lane = tid & 63;
    const int w    = tid >> 6;

    // ---- per-block constants ----
    for (int t = tid; t < NUMCEP * NFILT; t += 256) {
        int k = t / NFILT, j = t - k * NFILT;
        float v = cosf(PI_F * (float)((2 * j + 1) * k) / (2.0f * (float)NFILT));
        v *= (k == 0) ? rsqrtf((float)NFILT) : sqrtf(2.0f / (float)NFILT);
        dctm[k][j] = v;
    }
    if (tid < NFILT + 2) binsS[tid] = bins_g[tid];
    __syncthreads();

    // ---- pair identity ----
    const int gp = blockIdx.x * 4 + w;
    const int b  = gp / NPAIRS;
    const int g  = gp - b * NPAIRS;
    const int f0 = 2 * g;
    const int f1 = f0 + 1;
    const int len = lengths[b];
    const int nf  = (len <= FLEN) ? 1 : 1 + (len - FLEN + STEP - 1) / STEP;

    // ---- dead pair: both frames masked to zero -> write zeros, exit ----
    if (f0 >= nf) {
        int k = lane & 31;
        bool hi = lane >= 32;
        int f = hi ? f1 : f0;
        if (k < NUMCEP && f < NFRAMES)
            out[((long)b * NFRAMES + f) * NUMCEP + k] = 0.0f;
        return;   // no block barriers after this point
    }

    const float* s = sig + (long)b * TLEN;
    const int base = f0 * STEP;

    // ---- load: contiguous 8-sample chunk per lane (bit-reversed layout) ----
    // storage n = lane + 64*r holds x[brev9(n)] = x[8*brev6(lane) + brev3(r)]
    const int B   = (int)(__brev((unsigned)lane) >> 26);   // brev6
    const int i0  = 8 * B;
    const bool liveB = (i0 < FLEN);                         // FLEN = 400 = 8*50
    float w0[9], w1[9];
    {
        const int tb0 = base + i0 - 1;
        const int tb1 = tb0 + STEP;
        #pragma unroll
        for (int j = 0; j < 9; ++j) {
            int t0 = tb0 + j;
            w0[j] = (liveB && t0 >= 0 && t0 < len) ? s[t0] : 0.0f;
            int t1 = tb1 + j;
            w1[j] = (liveB && t1 < len) ? s[t1] : 0.0f;   // t1 >= 159 always
        }
    }

    // ---- per-lane twiddles: T = e^{-2*pi*i*lane/512}, powers by squaring ----
    float T1r, T1i;
    {
        float sn, cs;
        sincosf(-PI_F * (float)lane / 256.0f, &sn, &cs);
        T1r = cs; T1i = sn;
    }
#define SQC(orr, oii, ir, ii) { float _r = ir * ir - ii * ii; oii = 2.0f * ir * ii; orr = _r; }
    float T2r, T2i;   SQC(T2r, T2i, T1r, T1i)
    float T4r, T4i;   SQC(T4r, T4i, T2r, T2i)
    float T8r, T8i;   SQC(T8r, T8i, T4r, T4i)
    float T16r, T16i; SQC(T16r, T16i, T8r, T8i)
    float T32r, T32i; SQC(T32r, T32i, T16r, T16i)
    float T64r, T64i; SQC(T64r, T64i, T32r, T32i)
    float T128r, T128i; SQC(T128r, T128i, T64r, T64i)
    // A_q = T * W8^q  (W8 = e^{-i*pi/4})
    const float RH = 0.70710678118654752f;
    const float A1r = RH * (T1r + T1i), A1i = RH * (T1i - T1r);
    const float A2r = T1i,              A2i = -T1r;
    const float A3r = RH * (T1i - T1r), A3i = -RH * (T1r + T1i);

    // ---- assemble input registers (pre-emphasis; w0[0]=0 covers t==0) ----
    float zr[8], zi[8];
    {
        const int tbe = base + i0;     // frame0 sample index of element j
        #pragma unroll
        for (int r = 0; r < 8; ++r) {
            const int j = (r == 0) ? 0 : (r == 1) ? 4 : (r == 2) ? 2 : (r == 3) ? 6
                        : (r == 4) ? 1 : (r == 5) ? 5 : (r == 6) ? 3 : 7;  // brev3
            float v0 = fmaf(-0.97f, w0[j], w0[j + 1]);
            float v1 = fmaf(-0.97f, w1[j], w1[j + 1]);
            zr[r] = (liveB && (tbe + j) < len)        ? v0 : 0.0f;
            zi[r] = (liveB && (tbe + STEP + j) < len) ? v1 : 0.0f;
        }
    }

    // ---- cross-lane DIT stages d = 1,2,4,8,16,32 ----
    {   // d=1: W=1
        float sg = (lane & 1) ? -1.0f : 1.0f;
        #pragma unroll
        for (int r = 0; r < 8; ++r) {
            float pr = __shfl_xor(zr[r], 1);
            float pi = __shfl_xor(zi[r], 1);
            zr[r] = fmaf(sg, zr[r], pr);
            zi[r] = fmaf(sg, zi[r], pi);
        }
    }
#define XSTAGE(d, UR, UI)                                            \
    {                                                                \
        bool hi_ = (lane & (d)) != 0;                                \
        float ur = hi_ ? (UR) : 1.0f;                                \
        float ui = hi_ ? (UI) : 0.0f;                                \
        float sg = hi_ ? 1.0f : -1.0f;                               \
        _Pragma("unroll")                                            \
        for (int r = 0; r < 8; ++r) {                                \
            float tr = zr[r] * ur - zi[r] * ui;                      \
            float ti = zr[r] * ui + zi[r] * ur;                      \
            float pr = __shfl_xor(tr, (d));                          \
            float pi = __shfl_xor(ti, (d));                          \
            zr[r] = fmaf(sg, pr, tr);                                \
            zi[r] = fmaf(sg, pi, ti);                                \
        }                                                            \
    }
    XSTAGE(2,  T128r, T128i)
    XSTAGE(4,  T64r,  T64i)
    XSTAGE(8,  T32r,  T32i)
    XSTAGE(16, T16r,  T16i)
    XSTAGE(32, T8r,   T8i)

    // ---- in-register stages d = 64, 128, 256 ----
#define BFLY(a, bb, WR, WI)                                          \
    {                                                                \
        float tr = zr[bb] * (WR) - zi[bb] * (WI);                    \
        float ti = zr[bb] * (WI) + zi[bb] * (WR);                    \
        zr[bb] = zr[a] - tr; zi[bb] = zi[a] - ti;                    \
        zr[a] += tr;         zi[a] += ti;                            \
    }
    // d=64: pairs (2m,2m+1), W = T4
    BFLY(0, 1, T4r, T4i)  BFLY(2, 3, T4r, T4i)
    BFLY(4, 5, T4r, T4i)  BFLY(6, 7, T4r, T4i)
    // d=128: (0,2)(4,6) W=T2 ; (1,3)(5,7) W=T2*(-i)=(T2i,-T2r)
    BFLY(0, 2, T2r, T2i)  BFLY(4, 6, T2r, T2i)
    BFLY(1, 3, T2i, -T2r) BFLY(5, 7, T2i, -T2r)
    // d=256: (r,r+4), W = T1*W8^r
    BFLY(0, 4, T1r, T1i)
    BFLY(1, 5, A1r, A1i)
    BFLY(2, 6, A2r, A2i)
    BFLY(3, 7, A3r, A3i)

    // ---- unpack 2 real spectra + power + energy ----
    // Z[k] at lane=k&63, r=k>>6 (natural order). Pair k <-> 512-k.
    float* P0 = ps0[w];
    float* P1 = ps1[w];
    const float inv = 1.0f / (4.0f * (float)NFFT);
    float e0 = 0.0f, e1 = 0.0f;
    const int ml = (64 - lane) & 63;
    #pragma unroll
    for (int r = 0; r < 4; ++r) {
        float mr = __shfl(zr[7 - r], ml);
        float mi = __shfl(zi[7 - r], ml);
        if (lane == 0) { mr = zr[(8 - r) & 7]; mi = zi[(8 - r) & 7]; }
        float ar = zr[r] + mr, ai = zi[r] - mi;    // 2*X0
        float br = zi[r] + mi, bi = zr[r] - mr;    // 2j*X1 (same magnitude)
        float p0 = (ar * ar + ai * ai) * inv;
        float p1 = (br * br + bi * bi) * inv;
        P0[64 * r + lane] = p0;
        P1[64 * r + lane] = p1;
        e0 += p0; e1 += p1;
    }
    if (lane == 0) {   // k = 256: Z[256] = z[4], self-conjugate
        float p0 = 4.0f * zr[4] * zr[4] * inv;
        float p1 = 4.0f * zi[4] * zi[4] * inv;
        P0[256] = p0; P1[256] = p1;
        e0 += p0; e1 += p1;
    }
    #pragma unroll
    for (int off = 32; off >= 1; off >>= 1) {
        e0 += __shfl_xor(e0, off);
        e1 += __shfl_xor(e1, off);
    }
    __builtin_amdgcn_wave_barrier();

    // ---- mel filterbank via interval sums:
    //      feat[j] = U_j + (S_{j+1} - U_{j+1}),  intervals [bins[j],bins[j+1])
    const int  j  = lane & 31;
    const bool hi = lane >= 32;
    {
        const float* P = hi ? P1 : P0;
        float fu = 0.0f, fs = 0.0f;
        if (j <= NFILT) {              // j = 0..26
            int bA = binsS[j], bB = binsS[j + 1];
            for (int i = bA; i < bB; ++i) {
                float p = P[i];
                fs += p;
                fu = fmaf(p, (float)(i - bA), fu);
            }
            fu *= (bB > bA) ? 1.0f / (float)(bB - bA) : 0.0f;
        }
        float down  = fs - fu;
        float dnext = __shfl(down, lane + 1);
        if (j < NFILT) {
            float fv = logf(fu + dnext + EPSF);
            if (hi) feat1[w][j] = fv; else feat0[w][j] = fv;
        }
    }
    __builtin_amdgcn_wave_barrier();

    // ---- DCT + lifter + mask + store ----
    if (j < NUMCEP) {
        const float* ft = hi ? feat1[w] : feat0[w];
        float acc = 0.0f;
        #pragma unroll
        for (int jj = 0; jj < NFILT; ++jj)
            acc = fmaf(ft[jj], dctm[j][jj], acc);
        float lift = 1.0f + 11.0f * sinf(PI_F * (float)j / 22.0f);
        float val = acc * lift;
        if (j == 0) val = logf((hi ? e1 : e0) + EPSF);
        int f = hi ? f1 : f0;
        if (f < NFRAMES) {
            if (f >= nf) val = 0.0f;
            out[((long)b * NFRAMES + f) * NUMCEP + j] = val;
        }
    }
}

extern "C" void kernel_launch(void* const* d_in, const int* in_sizes, int n_in,
                              void* d_out, int out_size, void* d_ws, size_t ws_size,
                              hipStream_t stream) {
    const float* sig     = (const float*)d_in[0];
    const int*   lengths = (const int*)d_in[1];
    float* out  = (float*)d_out;
    int*   bins = (int*)d_ws;

    mfcc_setup_kernel<<<1, 64, 0, stream>>>(lengths, bins,
                                            out + (size_t)BATCH * NFRAMES * NUMCEP);

    const int total_pairs = BATCH * NPAIRS;      // 64000
    mfcc_kernel<<<total_pairs / 4, 256, 0, stream>>>(sig, lengths, bins, out);
}

// Round 4
// 77.366 us; speedup vs baseline: 5.3391x; 1.0572x over previous
//
#include <hip/hip_runtime.h>
#include <math.h>

#define SRATE   16000
#define FLEN    400
#define STEP    160
#define NFFT    512
#define NBINS   257
#define NFILT   26
#define NUMCEP  13
#define BATCH   64
#define TLEN    320000
#define NFRAMES 1999
#define NPAIRS  1000
#define EPSF    1.1920929e-07f
#define PI_F    3.14159265358979323846f

typedef float v2f __attribute__((ext_vector_type(2)));

__device__ __forceinline__ v2f mk2(float a, float b) { v2f v; v.x = a; v.y = b; return v; }
__device__ __forceinline__ v2f pfma(v2f a, v2f b, v2f c) { return __builtin_elementwise_fma(a, b, c); }

// ---------------------------------------------------------------------------
// Setup: mel bin edges (f64, matches numpy floor), lifted DCT matrix (f64),
// and the nframes output.
// ws layout: int bins[32] | float dctm_lift[NUMCEP*NFILT]
// ---------------------------------------------------------------------------
__global__ void mfcc_setup_kernel(const int* __restrict__ lengths,
                                  void* __restrict__ ws,
                                  float* __restrict__ out_nframes) {
    int tid = threadIdx.x;
    int*   bins = (int*)ws;
    float* dctw = (float*)ws + 32;

    if (tid < 28) {
        double M    = 2595.0 * log10(1.0 + 8000.0 / 700.0);
        double step = M / 27.0;
        double mel  = (tid == 27) ? M : (double)tid * step;
        double hz   = 700.0 * (pow(10.0, mel / 2595.0) - 1.0);
        bins[tid] = (int)floor((double)(NFFT + 1) * hz / (double)SRATE);
    }
    for (int t = tid; t < NUMCEP * NFILT; t += 64) {
        int k = t / NFILT, j = t - k * NFILT;
        double v = cos(M_PI * (double)((2 * j + 1) * k) / (2.0 * (double)NFILT));
        v *= (k == 0) ? 1.0 / sqrt((double)NFILT) : sqrt(2.0 / (double)NFILT);
        double lift = 1.0 + ((double)22 / 2.0) * sin(M_PI * (double)k / (double)22);
        dctw[t] = (float)(v * lift);
    }
    if (tid < BATCH) {
        int len = lengths[tid];
        int nf  = (len <= FLEN) ? 1 : 1 + (len - FLEN + STEP - 1) / STEP;
        out_nframes[tid] = (float)nf;
    }
}

// ---------------------------------------------------------------------------
// Main kernel: one wave per frame pair; packed-f32 all-register 512-pt FFT.
// Register packing: v2f Z[m] = (reg m, reg m+4) -> all cross-lane stages and
// d=64/128 in-register stages are componentwise (v_pk_fma_f32 rate).
// ---------------------------------------------------------------------------
__launch_bounds__(256)
__global__ void mfcc_kernel(const float* __restrict__ sig,
                            const int*   __restrict__ lengths,
                            const void*  __restrict__ ws,
                            float*       __restrict__ out) {
    __shared__ float ps0[4][NBINS + 3];
    __shared__ float ps1[4][NBINS + 3];
    __shared__ float feat0[4][28], feat1[4][28];
    __shared__ float dctS[NUMCEP * NFILT];
    __shared__ int   binsS[NFILT + 2];

    const int tid  = threadIdx.x;
    const int lane = tid & 63;
    const int w    = tid >> 6;

    // ---- per-block constants (from ws; no libm in the hot kernel) ----
    {
        const int*   binsG = (const int*)ws;
        const float* dctG  = (const float*)ws + 32;
        for (int t = tid; t < NUMCEP * NFILT; t += 256) dctS[t] = dctG[t];
        if (tid < NFILT + 2) binsS[tid] = binsG[tid];
    }
    __syncthreads();

    // ---- pair identity ----
    const int gp = blockIdx.x * 4 + w;
    const int b  = gp / NPAIRS;
    const int g  = gp - b * NPAIRS;
    const int f0 = 2 * g;
    const int f1 = f0 + 1;
    const int len = lengths[b];
    const int nf  = (len <= FLEN) ? 1 : 1 + (len - FLEN + STEP - 1) / STEP;

    // ---- dead pair: write zeros, exit (no block barriers after this) ----
    if (f0 >= nf) {
        int k = lane & 31;
        bool hi = lane >= 32;
        int f = hi ? f1 : f0;
        if (k < NUMCEP && f < NFRAMES)
            out[((long)b * NFRAMES + f) * NUMCEP + k] = 0.0f;
        return;
    }

    const float* s = sig + (long)b * TLEN;
    const int base = f0 * STEP;

    // ---- load: contiguous 8-sample chunk per lane (bit-reversed layout) ----
    const int B   = (int)(__brev((unsigned)lane) >> 26);   // brev6
    const int i0  = 8 * B;
    const bool liveB = (i0 < FLEN);
    float w0[9], w1[9];
    {
        const int tb0 = base + i0 - 1;
        const int tb1 = tb0 + STEP;
        #pragma unroll
        for (int j = 0; j < 9; ++j) {
            int t0 = tb0 + j;
            w0[j] = (liveB && t0 >= 0 && t0 < len) ? s[t0] : 0.0f;
            int t1 = tb1 + j;
            w1[j] = (liveB && t1 < len) ? s[t1] : 0.0f;
        }
    }

    // ---- per-lane twiddles ----
    float T1r, T1i;
    {
        float sn, cs;
        sincosf(-PI_F * (float)lane / 256.0f, &sn, &cs);
        T1r = cs; T1i = sn;
    }
#define SQC(orr, oii, ir, ii) { float _r = ir * ir - ii * ii; oii = 2.0f * ir * ii; orr = _r; }
    float T2r, T2i;   SQC(T2r, T2i, T1r, T1i)
    float T4r, T4i;   SQC(T4r, T4i, T2r, T2i)
    float T8r, T8i;   SQC(T8r, T8i, T4r, T4i)
    float T16r, T16i; SQC(T16r, T16i, T8r, T8i)
    float T32r, T32i; SQC(T32r, T32i, T16r, T16i)
    float T64r, T64i; SQC(T64r, T64i, T32r, T32i)
    float T128r, T128i; SQC(T128r, T128i, T64r, T64i)
    const float RH = 0.70710678118654752f;
    const float A1r = RH * (T1r + T1i), A1i = RH * (T1i - T1r);
    const float A2r = T1i,              A2i = -T1r;
    const float A3r = RH * (T1i - T1r), A3i = -RH * (T1r + T1i);

    // ---- assemble packed input: Z[m] = (elem JM[m], elem JM[m]+1) ----
    v2f Zr[4], Zi[4];
    {
        const int tbe = base + i0;
        #pragma unroll
        for (int m = 0; m < 4; ++m) {
            const int j = (m == 0) ? 0 : (m == 1) ? 4 : (m == 2) ? 2 : 6;  // brev3(m)
            float v0a = fmaf(-0.97f, w0[j],     w0[j + 1]);
            float v0b = fmaf(-0.97f, w0[j + 1], w0[j + 2]);
            float v1a = fmaf(-0.97f, w1[j],     w1[j + 1]);
            float v1b = fmaf(-0.97f, w1[j + 1], w1[j + 2]);
            bool ma = liveB && (tbe + j) < len;
            bool mb = liveB && (tbe + j + 1) < len;
            bool na = liveB && (tbe + STEP + j) < len;
            bool nb = liveB && (tbe + STEP + j + 1) < len;
            Zr[m] = mk2(ma ? v0a : 0.0f, mb ? v0b : 0.0f);
            Zi[m] = mk2(na ? v1a : 0.0f, nb ? v1b : 0.0f);
        }
    }

    // ---- cross-lane stage d=1 (W=1) ----
    {
        const float sg = (lane & 1) ? -1.0f : 1.0f;
        const v2f sg2 = mk2(sg, sg);
        #pragma unroll
        for (int m = 0; m < 4; ++m) {
            v2f pr = mk2(__shfl_xor(Zr[m].x, 1), __shfl_xor(Zr[m].y, 1));
            v2f pi = mk2(__shfl_xor(Zi[m].x, 1), __shfl_xor(Zi[m].y, 1));
            Zr[m] = pfma(sg2, Zr[m], pr);
            Zi[m] = pfma(sg2, Zi[m], pi);
        }
    }

    // ---- cross-lane stages d = 2..32 (packed) ----
#define PK_XSTAGE(d, UR, UI)                                                  \
    {                                                                         \
        const bool hi_ = (lane & (d)) != 0;                                   \
        const float ur = hi_ ? (UR) : 1.0f;                                   \
        const float ui = hi_ ? (UI) : 0.0f;                                   \
        const float sg = hi_ ? 1.0f : -1.0f;                                  \
        const v2f ur2 = mk2(ur, ur), ui2 = mk2(ui, ui);                       \
        const v2f nui2 = mk2(-ui, -ui), sg2 = mk2(sg, sg);                    \
        _Pragma("unroll")                                                     \
        for (int m = 0; m < 4; ++m) {                                         \
            v2f tr = pfma(Zi[m], nui2, Zr[m] * ur2);                          \
            v2f ti = pfma(Zi[m], ur2,  Zr[m] * ui2);                          \
            v2f pr = mk2(__shfl_xor(tr.x, (d)), __shfl_xor(tr.y, (d)));       \
            v2f pi = mk2(__shfl_xor(ti.x, (d)), __shfl_xor(ti.y, (d)));       \
            Zr[m] = pfma(sg2, pr, tr);                                        \
            Zi[m] = pfma(sg2, pi, ti);                                        \
        }                                                                     \
    }
    PK_XSTAGE(2,  T128r, T128i)
    PK_XSTAGE(4,  T64r,  T64i)
    PK_XSTAGE(8,  T32r,  T32i)
    PK_XSTAGE(16, T16r,  T16i)
    PK_XSTAGE(32, T8r,   T8i)

    // ---- in-register stages d=64, d=128 (packed, componentwise) ----
#define PBFLY(A, Bv, WR, WI)                                                  \
    {                                                                         \
        const v2f wr2 = mk2((WR), (WR)), wi2 = mk2((WI), (WI));               \
        const v2f nwi2 = mk2(-(WI), -(WI));                                   \
        v2f tr = pfma(Zi[Bv], nwi2, Zr[Bv] * wr2);                            \
        v2f ti = pfma(Zi[Bv], wr2,  Zr[Bv] * wi2);                            \
        Zr[Bv] = Zr[A] - tr;  Zi[Bv] = Zi[A] - ti;                            \
        Zr[A]  = Zr[A] + tr;  Zi[A]  = Zi[A] + ti;                            \
    }
    // d=64: reg pairs (0,1),(4,5) and (2,3),(6,7), W = T4
    PBFLY(0, 1, T4r, T4i)
    PBFLY(2, 3, T4r, T4i)
    // d=128: (0,2),(4,6) W=T2 ; (1,3),(5,7) W=T2*(-i)
    PBFLY(0, 2, T2r, T2i)
    PBFLY(1, 3, T2i, -T2r)

    // ---- final stage d=256: cross-component, scalar ----
    float zr[8], zi[8];
    {
        #pragma unroll
        for (int m = 0; m < 4; ++m) {
            const float Wr = (m == 0) ? T1r : (m == 1) ? A1r : (m == 2) ? A2r : A3r;
            const float Wi = (m == 0) ? T1i : (m == 1) ? A1i : (m == 2) ? A2i : A3i;
            float tr = Zr[m].y * Wr - Zi[m].y * Wi;
            float ti = Zr[m].y * Wi + Zi[m].y * Wr;
            zr[m]     = Zr[m].x + tr;  zi[m]     = Zi[m].x + ti;
            zr[m + 4] = Zr[m].x - tr;  zi[m + 4] = Zi[m].x - ti;
        }
    }

    // ---- unpack 2 real spectra + power + energy ----
    float* P0 = ps0[w];
    float* P1 = ps1[w];
    const float inv = 1.0f / (4.0f * (float)NFFT);
    float e0 = 0.0f, e1 = 0.0f;
    const int ml = (64 - lane) & 63;
    #pragma unroll
    for (int r = 0; r < 4; ++r) {
        float mr = __shfl(zr[7 - r], ml);
        float mi = __shfl(zi[7 - r], ml);
        if (lane == 0) { mr = zr[(8 - r) & 7]; mi = zi[(8 - r) & 7]; }
        float ar = zr[r] + mr, ai = zi[r] - mi;
        float br = zi[r] + mi, bi = zr[r] - mr;
        float p0 = (ar * ar + ai * ai) * inv;
        float p1 = (br * br + bi * bi) * inv;
        P0[64 * r + lane] = p0;
        P1[64 * r + lane] = p1;
        e0 += p0; e1 += p1;
    }
    if (lane == 0) {
        float p0 = 4.0f * zr[4] * zr[4] * inv;
        float p1 = 4.0f * zi[4] * zi[4] * inv;
        P0[256] = p0; P1[256] = p1;
        e0 += p0; e1 += p1;
    }
    v2f E = mk2(e0, e1);
    #pragma unroll
    for (int off = 32; off >= 1; off >>= 1)
        E = E + mk2(__shfl_xor(E.x, off), __shfl_xor(E.y, off));
    __builtin_amdgcn_wave_barrier();

    // ---- mel filterbank via interval sums ----
    const int  j  = lane & 31;
    const bool hi = lane >= 32;
    {
        const float* P = hi ? P1 : P0;
        float fu = 0.0f, fs = 0.0f;
        if (j <= NFILT) {
            int bA = binsS[j], bB = binsS[j + 1];
            for (int i = bA; i < bB; ++i) {
                float p = P[i];
                fs += p;
                fu = fmaf(p, (float)(i - bA), fu);
            }
            fu *= (bB > bA) ? 1.0f / (float)(bB - bA) : 0.0f;
        }
        float down  = fs - fu;
        float dnext = __shfl(down, lane + 1);
        if (j < NFILT) {
            float fv = logf(fu + dnext + EPSF);
            if (hi) feat1[w][j] = fv; else feat0[w][j] = fv;
        }
    }
    __builtin_amdgcn_wave_barrier();

    // ---- DCT (lifter pre-folded) + mask + store ----
    if (j < NUMCEP) {
        const float* ft = hi ? feat1[w] : feat0[w];
        float acc = 0.0f;
        #pragma unroll
        for (int jj = 0; jj < NFILT; ++jj)
            acc = fmaf(ft[jj], dctS[j * NFILT + jj], acc);
        float val = acc;
        if (j == 0) val = logf((hi ? E.y : E.x) + EPSF);
        int f = hi ? f1 : f0;
        if (f < NFRAMES) {
            if (f >= nf) val = 0.0f;
            out[((long)b * NFRAMES + f) * NUMCEP + j] = val;
        }
    }
}

extern "C" void kernel_launch(void* const* d_in, const int* in_sizes, int n_in,
                              void* d_out, int out_size, void* d_ws, size_t ws_size,
                              hipStream_t stream) {
    const float* sig     = (const float*)d_in[0];
    const int*   lengths = (const int*)d_in[1];
    float* out = (float*)d_out;

    mfcc_setup_kernel<<<1, 64, 0, stream>>>(lengths, d_ws,
                                            out + (size_t)BATCH * NFRAMES * NUMCEP);

    const int total_pairs = BATCH * NPAIRS;      // 64000
    mfcc_kernel<<<total_pairs / 4, 256, 0, stream>>>(sig, lengths, d_ws, out);
}

// Round 5
// 56.694 us; speedup vs baseline: 7.2859x; 1.3646x over previous
//
#include <hip/hip_runtime.h>
#include <math.h>

#define SRATE   16000
#define FLEN    400
#define STEP    160
#define NFFT    512
#define NBINS   257
#define NFILT   26
#define NUMCEP  13
#define BATCH   64
#define TLEN    320000
#define NFRAMES 1999
#define NPAIRS  1000
#define EPSF    1.1920929e-07f
#define PI_F    3.14159265358979323846f

typedef float    v2f __attribute__((ext_vector_type(2)));
typedef unsigned uv2 __attribute__((ext_vector_type(2)));

__device__ __forceinline__ v2f mk2(float a, float b) { v2f v; v.x = a; v.y = b; return v; }
__device__ __forceinline__ v2f pfma(v2f a, v2f b, v2f c) { return __builtin_elementwise_fma(a, b, c); }

// Cross-lane primitives (all full-wave-active call sites):
template<int CTRL>
__device__ __forceinline__ float fdpp(float x) {   // DPP: VALU pipe, ~2cyc
    return __builtin_bit_cast(float, __builtin_amdgcn_mov_dpp(
        __builtin_bit_cast(int, x), CTRL, 0xF, 0xF, true));
}
template<int IMM>
__device__ __forceinline__ float fswz(float x) {   // ds_swizzle: DS pipe, no idx setup
    return __builtin_bit_cast(float, __builtin_amdgcn_ds_swizzle(
        __builtin_bit_cast(int, x), IMM));
}
__device__ __forceinline__ uv2 pl32(float x) {     // permlane32_swap: VALU pipe
    unsigned u = __builtin_bit_cast(unsigned, x);
    return __builtin_amdgcn_permlane32_swap(u, u, false, false);
}
__device__ __forceinline__ float fxor32(float x, bool hi32) {
    uv2 r = pl32(x);
    return __builtin_bit_cast(float, hi32 ? r[0] : r[1]);
}
#define DPP_X1   0xB1   // quad_perm [1,0,3,2]  = xor 1
#define DPP_X2   0x4E   // quad_perm [2,3,0,1]  = xor 2
#define DPP_X8   0x128  // row_ror:8            = xor 8
#define SWZ_X4   0x101F // BitMode xor 4
#define SWZ_X16  0x401F // BitMode xor 16

// ---------------------------------------------------------------------------
// Setup: mel bin edges (f64, matches numpy floor), lifted DCT matrix (f64),
// and the nframes output.  ws: int bins[32] | float dctm_lift[NUMCEP*NFILT]
// ---------------------------------------------------------------------------
__global__ void mfcc_setup_kernel(const int* __restrict__ lengths,
                                  void* __restrict__ ws,
                                  float* __restrict__ out_nframes) {
    int tid = threadIdx.x;
    int*   bins = (int*)ws;
    float* dctw = (float*)ws + 32;

    if (tid < 28) {
        double M    = 2595.0 * log10(1.0 + 8000.0 / 700.0);
        double step = M / 27.0;
        double mel  = (tid == 27) ? M : (double)tid * step;
        double hz   = 700.0 * (pow(10.0, mel / 2595.0) - 1.0);
        bins[tid] = (int)floor((double)(NFFT + 1) * hz / (double)SRATE);
    }
    for (int t = tid; t < NUMCEP * NFILT; t += 64) {
        int k = t / NFILT, j = t - k * NFILT;
        double v = cos(M_PI * (double)((2 * j + 1) * k) / (2.0 * (double)NFILT));
        v *= (k == 0) ? 1.0 / sqrt((double)NFILT) : sqrt(2.0 / (double)NFILT);
        double lift = 1.0 + 11.0 * sin(M_PI * (double)k / 22.0);
        dctw[t] = (float)(v * lift);
    }
    if (tid < BATCH) {
        int len = lengths[tid];
        int nf  = (len <= FLEN) ? 1 : 1 + (len - FLEN + STEP - 1) / STEP;
        out_nframes[tid] = (float)nf;
    }
}

// ---------------------------------------------------------------------------
// Main kernel: one wave per frame pair; packed-f32 all-register 512-pt FFT.
// ---------------------------------------------------------------------------
__launch_bounds__(256)
__global__ void mfcc_kernel(const float* __restrict__ sig,
                            const int*   __restrict__ lengths,
                            const void*  __restrict__ ws,
                            float*       __restrict__ out) {
    __shared__ float ps0[4][NBINS + 3];
    __shared__ float ps1[4][NBINS + 3];
    __shared__ float feat0[4][28], feat1[4][28];
    __shared__ float dctS[NUMCEP * NFILT];
    __shared__ int   binsS[NFILT + 2];

    const int tid  = threadIdx.x;
    const int lane = tid & 63;
    const int w    = tid >> 6;

    // ---- per-block constants ----
    {
        const int*   binsG = (const int*)ws;
        const float* dctG  = (const float*)ws + 32;
        for (int t = tid; t < NUMCEP * NFILT; t += 256) dctS[t] = dctG[t];
        if (tid < NFILT + 2) binsS[tid] = binsG[tid];
    }
    __syncthreads();

    // ---- pair identity ----
    const int gp = blockIdx.x * 4 + w;
    const int b  = gp / NPAIRS;
    const int g  = gp - b * NPAIRS;
    const int f0 = 2 * g;
    const int f1 = f0 + 1;
    const int len = lengths[b];
    const int nf  = (len <= FLEN) ? 1 : 1 + (len - FLEN + STEP - 1) / STEP;

    // ---- dead pair: write zeros, exit (no block barriers after this) ----
    if (f0 >= nf) {
        int k = lane & 31;
        bool hi = lane >= 32;
        int f = hi ? f1 : f0;
        if (k < NUMCEP && f < NFRAMES)
            out[((long)b * NFRAMES + f) * NUMCEP + k] = 0.0f;
        return;
    }

    const float* s = sig + (long)b * TLEN;
    const int base = f0 * STEP;

    const int B   = (int)(__brev((unsigned)lane) >> 26);   // brev6
    const int i0  = 8 * B;
    const bool liveB = (i0 < FLEN);

    // ---- load + pre-emphasis + mask -> packed FFT input registers ----
    v2f Zr[4], Zi[4];
    const bool fastw = (base >= 1) && (base + 560 <= len);  // wave-uniform
    if (fastw) {
        // hot path: all samples in-bounds and live -> no guards at all
        float w0[9], w1[9];
        if (liveB) {
            const int tb0 = base + i0 - 1;
            #pragma unroll
            for (int j = 0; j < 9; ++j) {
                w0[j] = s[tb0 + j];
                w1[j] = s[tb0 + STEP + j];
            }
        } else {
            #pragma unroll
            for (int j = 0; j < 9; ++j) { w0[j] = 0.0f; w1[j] = 0.0f; }
        }
        #pragma unroll
        for (int m = 0; m < 4; ++m) {
            const int j = (m == 0) ? 0 : (m == 1) ? 4 : (m == 2) ? 2 : 6;  // brev3
            Zr[m] = mk2(fmaf(-0.97f, w0[j],     w0[j + 1]),
                        fmaf(-0.97f, w0[j + 1], w0[j + 2]));
            Zi[m] = mk2(fmaf(-0.97f, w1[j],     w1[j + 1]),
                        fmaf(-0.97f, w1[j + 1], w1[j + 2]));
        }
    } else {
        // boundary path (~1% of live waves): full guards (R4-validated)
        float w0[9], w1[9];
        const int tb0 = base + i0 - 1;
        const int tb1 = tb0 + STEP;
        #pragma unroll
        for (int j = 0; j < 9; ++j) {
            int t0 = tb0 + j;
            w0[j] = (liveB && t0 >= 0 && t0 < len) ? s[t0] : 0.0f;
            int t1 = tb1 + j;
            w1[j] = (liveB && t1 < len) ? s[t1] : 0.0f;
        }
        const int tbe = base + i0;
        #pragma unroll
        for (int m = 0; m < 4; ++m) {
            const int j = (m == 0) ? 0 : (m == 1) ? 4 : (m == 2) ? 2 : 6;
            float v0a = fmaf(-0.97f, w0[j],     w0[j + 1]);
            float v0b = fmaf(-0.97f, w0[j + 1], w0[j + 2]);
            float v1a = fmaf(-0.97f, w1[j],     w1[j + 1]);
            float v1b = fmaf(-0.97f, w1[j + 1], w1[j + 2]);
            bool ma = liveB && (tbe + j) < len;
            bool mb = liveB && (tbe + j + 1) < len;
            bool na = liveB && (tbe + STEP + j) < len;
            bool nb = liveB && (tbe + STEP + j + 1) < len;
            Zr[m] = mk2(ma ? v0a : 0.0f, mb ? v0b : 0.0f);
            Zi[m] = mk2(na ? v1a : 0.0f, nb ? v1b : 0.0f);
        }
    }

    // ---- per-lane twiddles: T = e^{-2*pi*i*lane/512} (HW v_sin/v_cos) ----
    const float ang = -PI_F * (float)lane / 256.0f;
    float T1i = __sinf(ang);
    float T1r = __cosf(ang);
#define SQC(orr, oii, ir, ii) { float _r = ir * ir - ii * ii; oii = 2.0f * ir * ii; orr = _r; }
    float T2r, T2i;   SQC(T2r, T2i, T1r, T1i)
    float T4r, T4i;   SQC(T4r, T4i, T2r, T2i)
    float T8r, T8i;   SQC(T8r, T8i, T4r, T4i)
    float T16r, T16i; SQC(T16r, T16i, T8r, T8i)
    float T32r, T32i; SQC(T32r, T32i, T16r, T16i)
    float T64r, T64i; SQC(T64r, T64i, T32r, T32i)
    float T128r, T128i; SQC(T128r, T128i, T64r, T64i)
    const float RH = 0.70710678118654752f;
    const float A1r = RH * (T1r + T1i), A1i = RH * (T1i - T1r);
    const float A2r = T1i,              A2i = -T1r;
    const float A3r = RH * (T1i - T1r), A3i = -RH * (T1r + T1i);

    // ---- cross-lane stage d=1 (W=1): DPP quad_perm ----
    {
        const float sg = (lane & 1) ? -1.0f : 1.0f;
        const v2f sg2 = mk2(sg, sg);
        #pragma unroll
        for (int m = 0; m < 4; ++m) {
            v2f pr = mk2(fdpp<DPP_X1>(Zr[m].x), fdpp<DPP_X1>(Zr[m].y));
            v2f pi = mk2(fdpp<DPP_X1>(Zi[m].x), fdpp<DPP_X1>(Zi[m].y));
            Zr[m] = pfma(sg2, Zr[m], pr);
            Zi[m] = pfma(sg2, Zi[m], pi);
        }
    }

    // ---- cross-lane stages d = 2..32 (packed; per-distance shuffle prim) ----
#define PK_XSTAGE_G(d, UR, UI, SH)                                            \
    {                                                                         \
        const bool hi_ = (lane & (d)) != 0;                                   \
        const float ur = hi_ ? (UR) : 1.0f;                                   \
        const float ui = hi_ ? (UI) : 0.0f;                                   \
        const float sg = hi_ ? 1.0f : -1.0f;                                  \
        const v2f ur2 = mk2(ur, ur), ui2 = mk2(ui, ui);                       \
        const v2f nui2 = mk2(-ui, -ui), sg2 = mk2(sg, sg);                    \
        _Pragma("unroll")                                                     \
        for (int m = 0; m < 4; ++m) {                                         \
            v2f tr = pfma(Zi[m], nui2, Zr[m] * ur2);                          \
            v2f ti = pfma(Zi[m], ur2,  Zr[m] * ui2);                          \
            v2f pr = mk2(SH(tr.x), SH(tr.y));                                 \
            v2f pi = mk2(SH(ti.x), SH(ti.y));                                 \
            Zr[m] = pfma(sg2, pr, tr);                                        \
            Zi[m] = pfma(sg2, pi, ti);                                        \
        }                                                                     \
    }
#define SH_X2(v)  fdpp<DPP_X2>(v)
#define SH_X4(v)  fswz<SWZ_X4>(v)
#define SH_X8(v)  fdpp<DPP_X8>(v)
#define SH_X16(v) fswz<SWZ_X16>(v)
#define SH_X32(v) fxor32(v, hi_)
    PK_XSTAGE_G(2,  T128r, T128i, SH_X2)
    PK_XSTAGE_G(4,  T64r,  T64i,  SH_X4)
    PK_XSTAGE_G(8,  T32r,  T32i,  SH_X8)
    PK_XSTAGE_G(16, T16r,  T16i,  SH_X16)
    PK_XSTAGE_G(32, T8r,   T8i,   SH_X32)

    // ---- in-register stages d=64, d=128 (packed, componentwise) ----
#define PBFLY(A, Bv, WR, WI)                                                  \
    {                                                                         \
        const v2f wr2 = mk2((WR), (WR)), wi2 = mk2((WI), (WI));               \
        const v2f nwi2 = mk2(-(WI), -(WI));                                   \
        v2f tr = pfma(Zi[Bv], nwi2, Zr[Bv] * wr2);                            \
        v2f ti = pfma(Zi[Bv], wr2,  Zr[Bv] * wi2);                            \
        Zr[Bv] = Zr[A] - tr;  Zi[Bv] = Zi[A] - ti;                            \
        Zr[A]  = Zr[A] + tr;  Zi[A]  = Zi[A] + ti;                            \
    }
    PBFLY(0, 1, T4r, T4i)
    PBFLY(2, 3, T4r, T4i)
    PBFLY(0, 2, T2r, T2i)
    PBFLY(1, 3, T2i, -T2r)

    // ---- final stage d=256: cross-component, scalar ----
    float zr[8], zi[8];
    {
        #pragma unroll
        for (int m = 0; m < 4; ++m) {
            const float Wr = (m == 0) ? T1r : (m == 1) ? A1r : (m == 2) ? A2r : A3r;
            const float Wi = (m == 0) ? T1i : (m == 1) ? A1i : (m == 2) ? A2i : A3i;
            float tr = Zr[m].y * Wr - Zi[m].y * Wi;
            float ti = Zr[m].y * Wi + Zi[m].y * Wr;
            zr[m]     = Zr[m].x + tr;  zi[m]     = Zi[m].x + ti;
            zr[m + 4] = Zr[m].x - tr;  zi[m + 4] = Zi[m].x - ti;
        }
    }

    // ---- unpack 2 real spectra + power + energy ----
    float* P0 = ps0[w];
    float* P1 = ps1[w];
    const float inv = 1.0f / (4.0f * (float)NFFT);
    float e0 = 0.0f, e1 = 0.0f;
    const int ml = (64 - lane) & 63;
    #pragma unroll
    for (int r = 0; r < 4; ++r) {
        float mr = __shfl(zr[7 - r], ml);
        float mi = __shfl(zi[7 - r], ml);
        if (lane == 0) { mr = zr[(8 - r) & 7]; mi = zi[(8 - r) & 7]; }
        float ar = zr[r] + mr, ai = zi[r] - mi;
        float br = zi[r] + mi, bi = zr[r] - mr;
        float p0 = (ar * ar + ai * ai) * inv;
        float p1 = (br * br + bi * bi) * inv;
        P0[64 * r + lane] = p0;
        P1[64 * r + lane] = p1;
        e0 += p0; e1 += p1;
    }
    if (lane == 0) {
        float p0 = 4.0f * zr[4] * zr[4] * inv;
        float p1 = 4.0f * zi[4] * zi[4] * inv;
        P0[256] = p0; P1[256] = p1;
        e0 += p0; e1 += p1;
    }
    v2f E = mk2(e0, e1);
    E = E + mk2(fdpp<DPP_X1>(E.x),  fdpp<DPP_X1>(E.y));
    E = E + mk2(fdpp<DPP_X2>(E.x),  fdpp<DPP_X2>(E.y));
    E = E + mk2(fswz<SWZ_X4>(E.x),  fswz<SWZ_X4>(E.y));
    E = E + mk2(fdpp<DPP_X8>(E.x),  fdpp<DPP_X8>(E.y));
    E = E + mk2(fswz<SWZ_X16>(E.x), fswz<SWZ_X16>(E.y));
    {
        uv2 rx = pl32(E.x), ry = pl32(E.y);
        E = mk2(__builtin_bit_cast(float, rx[0]) + __builtin_bit_cast(float, rx[1]),
                __builtin_bit_cast(float, ry[0]) + __builtin_bit_cast(float, ry[1]));
    }
    __builtin_amdgcn_wave_barrier();

    // ---- mel filterbank via interval sums (2-way unrolled chains) ----
    const int  j  = lane & 31;
    const bool hi = lane >= 32;
    {
        const float* P = hi ? P1 : P0;
        float fu = 0.0f, fs = 0.0f, fu2 = 0.0f, fs2 = 0.0f;
        if (j <= NFILT) {
            int bA = binsS[j], bB = binsS[j + 1];
            int i = bA;
            for (; i + 1 < bB; i += 2) {
                float p = P[i], q = P[i + 1];
                fs  += p;  fu  = fmaf(p, (float)(i - bA), fu);
                fs2 += q;  fu2 = fmaf(q, (float)(i + 1 - bA), fu2);
            }
            if (i < bB) {
                float p = P[i];
                fs += p;  fu = fmaf(p, (float)(i - bA), fu);
            }
            fs += fs2;  fu += fu2;
            fu *= (bB > bA) ? 1.0f / (float)(bB - bA) : 0.0f;
        }
        float down  = fs - fu;
        float dnext = __shfl(down, lane + 1);
        if (j < NFILT) {
            float fv = logf(fu + dnext + EPSF);
            if (hi) feat1[w][j] = fv; else feat0[w][j] = fv;
        }
    }
    __builtin_amdgcn_wave_barrier();

    // ---- DCT (lifter pre-folded, split accumulators) + mask + store ----
    if (j < NUMCEP) {
        const float* ft = hi ? feat1[w] : feat0[w];
        float a0 = 0.0f, a1 = 0.0f;
        #pragma unroll
        for (int jj = 0; jj < NFILT; jj += 2) {
            a0 = fmaf(ft[jj],     dctS[j * NFILT + jj],     a0);
            a1 = fmaf(ft[jj + 1], dctS[j * NFILT + jj + 1], a1);
        }
        float val = a0 + a1;
        if (j == 0) val = logf((hi ? E.y : E.x) + EPSF);
        int f = hi ? f1 : f0;
        if (f < NFRAMES) {
            if (f >= nf) val = 0.0f;
            out[((long)b * NFRAMES + f) * NUMCEP + j] = val;
        }
    }
}

extern "C" void kernel_launch(void* const* d_in, const int* in_sizes, int n_in,
                              void* d_out, int out_size, void* d_ws, size_t ws_size,
                              hipStream_t stream) {
    const float* sig     = (const float*)d_in[0];
    const int*   lengths = (const int*)d_in[1];
    float* out = (float*)d_out;

    mfcc_setup_kernel<<<1, 64, 0, stream>>>(lengths, d_ws,
                                            out + (size_t)BATCH * NFRAMES * NUMCEP);

    const int total_pairs = BATCH * NPAIRS;      // 64000
    mfcc_kernel<<<total_pairs / 4, 256, 0, stream>>>(sig, lengths, d_ws, out);
}

// Round 6
// 51.609 us; speedup vs baseline: 8.0037x; 1.0985x over previous
//
#include <hip/hip_runtime.h>
#include <math.h>

#define SRATE   16000
#define FLEN    400
#define STEP    160
#define NFFT    512
#define NBINS   257
#define NFILT   26
#define NUMCEP  13
#define BATCH   64
#define TLEN    320000
#define NFRAMES 1999
#define NGRP    500           // frame quads per batch element (4q .. 4q+3)
#define EPSF    1.1920929e-07f
#define PI_F    3.14159265358979323846f

typedef float    v2f __attribute__((ext_vector_type(2)));
typedef unsigned uv2 __attribute__((ext_vector_type(2)));

__device__ __forceinline__ v2f mk2(float a, float b) { v2f v; v.x = a; v.y = b; return v; }
__device__ __forceinline__ v2f pfma(v2f a, v2f b, v2f c) { return __builtin_elementwise_fma(a, b, c); }

template<int CTRL>
__device__ __forceinline__ float fdpp(float x) {   // DPP: VALU pipe
    return __builtin_bit_cast(float, __builtin_amdgcn_mov_dpp(
        __builtin_bit_cast(int, x), CTRL, 0xF, 0xF, true));
}
template<int IMM>
__device__ __forceinline__ float fswz(float x) {   // ds_swizzle
    return __builtin_bit_cast(float, __builtin_amdgcn_ds_swizzle(
        __builtin_bit_cast(int, x), IMM));
}
__device__ __forceinline__ uv2 pl32(float x) {     // permlane32_swap
    unsigned u = __builtin_bit_cast(unsigned, x);
    return __builtin_amdgcn_permlane32_swap(u, u, false, false);
}
__device__ __forceinline__ float fxor32(float x, bool hi32) {
    uv2 r = pl32(x);
    return __builtin_bit_cast(float, hi32 ? r[0] : r[1]);
}
#define DPP_X1   0xB1
#define DPP_X2   0x4E
#define DPP_X8   0x128
#define SWZ_X4   0x101F
#define SWZ_X16  0x401F

// ---------------------------------------------------------------------------
// Setup: mel bin edges (f64, matches numpy floor), lifted DCT matrix (f64),
// and the nframes output.  ws: int bins[32] | float dctm_lift[NUMCEP*NFILT]
// ---------------------------------------------------------------------------
__global__ void mfcc_setup_kernel(const int* __restrict__ lengths,
                                  void* __restrict__ ws,
                                  float* __restrict__ out_nframes) {
    int tid = threadIdx.x;
    int*   bins = (int*)ws;
    float* dctw = (float*)ws + 32;

    if (tid < 28) {
        double M    = 2595.0 * log10(1.0 + 8000.0 / 700.0);
        double step = M / 27.0;
        double mel  = (tid == 27) ? M : (double)tid * step;
        double hz   = 700.0 * (pow(10.0, mel / 2595.0) - 1.0);
        bins[tid] = (int)floor((double)(NFFT + 1) * hz / (double)SRATE);
    }
    for (int t = tid; t < NUMCEP * NFILT; t += 64) {
        int k = t / NFILT, j = t - k * NFILT;
        double v = cos(M_PI * (double)((2 * j + 1) * k) / (2.0 * (double)NFILT));
        v *= (k == 0) ? 1.0 / sqrt((double)NFILT) : sqrt(2.0 / (double)NFILT);
        double lift = 1.0 + 11.0 * sin(M_PI * (double)k / 22.0);
        dctw[t] = (float)(v * lift);
    }
    if (tid < BATCH) {
        int len = lengths[tid];
        int nf  = (len <= FLEN) ? 1 : 1 + (len - FLEN + STEP - 1) / STEP;
        out_nframes[tid] = (float)nf;
    }
}

// ---------------------------------------------------------------------------
// Main kernel: one wave per frame QUAD (two packed-real 512-pt FFTs,
// interleaved for ILP). Both frames of each pair live in v2f lanes.
// ---------------------------------------------------------------------------
__launch_bounds__(256)
__global__ void mfcc_kernel(const float* __restrict__ sig,
                            const int*   __restrict__ lengths,
                            const void*  __restrict__ ws,
                            float*       __restrict__ out) {
    __shared__ v2f psA[4][260];          // pair0 pspec, frames (f0,f0+1) packed
    __shared__ v2f psB[4][260];          // pair1 pspec, frames (f0+2,f0+3)
    __shared__ v2f featAs[4][28], featBs[4][28];
    __shared__ float dctS[NUMCEP * NFILT];
    __shared__ int   binsS[NFILT + 2];

    const int tid  = threadIdx.x;
    const int lane = tid & 63;
    const int w    = tid >> 6;

    {
        const int*   binsG = (const int*)ws;
        const float* dctG  = (const float*)ws + 32;
        for (int t = tid; t < NUMCEP * NFILT; t += 256) dctS[t] = dctG[t];
        if (tid < NFILT + 2) binsS[tid] = binsG[tid];
    }
    __syncthreads();

    // ---- quad identity ----
    const int G  = blockIdx.x * 4 + w;          // 0 .. 31999
    const int b  = G / NGRP;
    const int q  = G - b * NGRP;
    const int f0 = 4 * q;
    const int len = lengths[b];
    const int nf  = (len <= FLEN) ? 1 : 1 + (len - FLEN + STEP - 1) / STEP;

    // ---- dead quad: write zeros, exit ----
    if (f0 >= nf) {
        if (lane < 52) {
            int d13 = lane / 13;
            int kk  = lane - 13 * d13;
            int ff  = f0 + d13;
            if (ff < NFRAMES)
                out[((long)b * NFRAMES + ff) * NUMCEP + kk] = 0.0f;
        }
        return;
    }

    const float* s = sig + (long)b * TLEN;
    const int base = f0 * STEP;

    const int B   = (int)(__brev((unsigned)lane) >> 26);   // brev6
    const int i0  = 8 * B;
    const bool liveB = (i0 < FLEN);

    // ---- load + pre-emphasis + mask -> two packed FFT states ----
    v2f Zr0[4], Zi0[4], Zr1[4], Zi1[4];
    const bool fastw = (base >= 1) && (base + 880 <= len);  // wave-uniform
    if (fastw) {
        float w0[9], w1[9], w2[9], w3[9];
        if (liveB) {
            const int tb0 = base + i0 - 1;
            #pragma unroll
            for (int j = 0; j < 9; ++j) {
                w0[j] = s[tb0 + j];
                w1[j] = s[tb0 + 160 + j];
                w2[j] = s[tb0 + 320 + j];
                w3[j] = s[tb0 + 480 + j];
            }
        } else {
            #pragma unroll
            for (int j = 0; j < 9; ++j) { w0[j] = w1[j] = w2[j] = w3[j] = 0.0f; }
        }
        #pragma unroll
        for (int m = 0; m < 4; ++m) {
            const int j = (m == 0) ? 0 : (m == 1) ? 4 : (m == 2) ? 2 : 6;  // brev3
            Zr0[m] = mk2(fmaf(-0.97f, w0[j],     w0[j + 1]),
                         fmaf(-0.97f, w0[j + 1], w0[j + 2]));
            Zi0[m] = mk2(fmaf(-0.97f, w1[j],     w1[j + 1]),
                         fmaf(-0.97f, w1[j + 1], w1[j + 2]));
            Zr1[m] = mk2(fmaf(-0.97f, w2[j],     w2[j + 1]),
                         fmaf(-0.97f, w2[j + 1], w2[j + 2]));
            Zi1[m] = mk2(fmaf(-0.97f, w3[j],     w3[j + 1]),
                         fmaf(-0.97f, w3[j + 1], w3[j + 2]));
        }
    } else {
        float w0[9], w1[9], w2[9], w3[9];
        const int tb0 = base + i0 - 1;
        #pragma unroll
        for (int j = 0; j < 9; ++j) {
            int t0 = tb0 + j;
            w0[j] = (liveB && t0 >= 0 && t0 < len) ? s[t0] : 0.0f;
            int t1 = t0 + 160; w1[j] = (liveB && t1 < len) ? s[t1] : 0.0f;
            int t2 = t0 + 320; w2[j] = (liveB && t2 < len) ? s[t2] : 0.0f;
            int t3 = t0 + 480; w3[j] = (liveB && t3 < len) ? s[t3] : 0.0f;
        }
        const int tbe = base + i0;
        #pragma unroll
        for (int m = 0; m < 4; ++m) {
            const int j = (m == 0) ? 0 : (m == 1) ? 4 : (m == 2) ? 2 : 6;
#define ASMW(Wk, OFF, DST)                                                    \
            { float va = fmaf(-0.97f, Wk[j],     Wk[j + 1]);                  \
              float vb = fmaf(-0.97f, Wk[j + 1], Wk[j + 2]);                  \
              bool ma = liveB && (tbe + (OFF) + j)     < len;                 \
              bool mb = liveB && (tbe + (OFF) + j + 1) < len;                 \
              DST = mk2(ma ? va : 0.0f, mb ? vb : 0.0f); }
            ASMW(w0, 0,   Zr0[m])
            ASMW(w1, 160, Zi0[m])
            ASMW(w2, 320, Zr1[m])
            ASMW(w3, 480, Zi1[m])
#undef ASMW
        }
    }

    // ---- per-lane twiddles (shared by both FFTs) ----
    const float ang = -PI_F * (float)lane / 256.0f;
    float T1i = __sinf(ang);
    float T1r = __cosf(ang);
#define SQC(orr, oii, ir, ii) { float _r = ir * ir - ii * ii; oii = 2.0f * ir * ii; orr = _r; }
    float T2r, T2i;   SQC(T2r, T2i, T1r, T1i)
    float T4r, T4i;   SQC(T4r, T4i, T2r, T2i)
    float T8r, T8i;   SQC(T8r, T8i, T4r, T4i)
    float T16r, T16i; SQC(T16r, T16i, T8r, T8i)
    float T32r, T32i; SQC(T32r, T32i, T16r, T16i)
    float T64r, T64i; SQC(T64r, T64i, T32r, T32i)
    float T128r, T128i; SQC(T128r, T128i, T64r, T64i)
    const float RH = 0.70710678118654752f;
    const float A1r = RH * (T1r + T1i), A1i = RH * (T1i - T1r);
    const float A2r = T1i,              A2i = -T1r;
    const float A3r = RH * (T1i - T1r), A3i = -RH * (T1r + T1i);

    // ---- cross-lane stage d=1 (both FFTs) ----
    {
        const float sg = (lane & 1) ? -1.0f : 1.0f;
        const v2f sg2 = mk2(sg, sg);
        #pragma unroll
        for (int m = 0; m < 4; ++m) {
            v2f pr = mk2(fdpp<DPP_X1>(Zr0[m].x), fdpp<DPP_X1>(Zr0[m].y));
            v2f pi = mk2(fdpp<DPP_X1>(Zi0[m].x), fdpp<DPP_X1>(Zi0[m].y));
            Zr0[m] = pfma(sg2, Zr0[m], pr);
            Zi0[m] = pfma(sg2, Zi0[m], pi);
        }
        #pragma unroll
        for (int m = 0; m < 4; ++m) {
            v2f pr = mk2(fdpp<DPP_X1>(Zr1[m].x), fdpp<DPP_X1>(Zr1[m].y));
            v2f pi = mk2(fdpp<DPP_X1>(Zi1[m].x), fdpp<DPP_X1>(Zi1[m].y));
            Zr1[m] = pfma(sg2, Zr1[m], pr);
            Zi1[m] = pfma(sg2, Zi1[m], pi);
        }
    }

    // ---- cross-lane stages d = 2..32 (both FFTs interleaved) ----
#define PK_XSTAGE2(d, UR, UI, SH)                                             \
    {                                                                         \
        const bool hi_ = (lane & (d)) != 0;                                   \
        const float ur = hi_ ? (UR) : 1.0f;                                   \
        const float ui = hi_ ? (UI) : 0.0f;                                   \
        const float sg = hi_ ? 1.0f : -1.0f;                                  \
        const v2f ur2 = mk2(ur, ur), ui2 = mk2(ui, ui);                       \
        const v2f nui2 = mk2(-ui, -ui), sg2 = mk2(sg, sg);                    \
        _Pragma("unroll")                                                     \
        for (int m = 0; m < 4; ++m) {                                         \
            v2f tr = pfma(Zi0[m], nui2, Zr0[m] * ur2);                        \
            v2f ti = pfma(Zi0[m], ur2,  Zr0[m] * ui2);                        \
            v2f pr = mk2(SH(tr.x), SH(tr.y));                                 \
            v2f pi = mk2(SH(ti.x), SH(ti.y));                                 \
            Zr0[m] = pfma(sg2, pr, tr);                                       \
            Zi0[m] = pfma(sg2, pi, ti);                                       \
        }                                                                     \
        _Pragma("unroll")                                                     \
        for (int m = 0; m < 4; ++m) {                                         \
            v2f tr = pfma(Zi1[m], nui2, Zr1[m] * ur2);                        \
            v2f ti = pfma(Zi1[m], ur2,  Zr1[m] * ui2);                        \
            v2f pr = mk2(SH(tr.x), SH(tr.y));                                 \
            v2f pi = mk2(SH(ti.x), SH(ti.y));                                 \
            Zr1[m] = pfma(sg2, pr, tr);                                       \
            Zi1[m] = pfma(sg2, pi, ti);                                       \
        }                                                                     \
    }
#define SH_X2(v)  fdpp<DPP_X2>(v)
#define SH_X4(v)  fswz<SWZ_X4>(v)
#define SH_X8(v)  fdpp<DPP_X8>(v)
#define SH_X16(v) fswz<SWZ_X16>(v)
#define SH_X32(v) fxor32(v, hi_)
    PK_XSTAGE2(2,  T128r, T128i, SH_X2)
    PK_XSTAGE2(4,  T64r,  T64i,  SH_X4)
    PK_XSTAGE2(8,  T32r,  T32i,  SH_X8)
    PK_XSTAGE2(16, T16r,  T16i,  SH_X16)
    PK_XSTAGE2(32, T8r,   T8i,   SH_X32)

    // ---- in-register stages d=64, d=128 (both FFTs) ----
#define PBFLY2(A, Bv, WR, WI)                                                 \
    {                                                                         \
        const v2f wr2 = mk2((WR), (WR)), wi2 = mk2((WI), (WI));               \
        const v2f nwi2 = mk2(-(WI), -(WI));                                   \
        { v2f tr = pfma(Zi0[Bv], nwi2, Zr0[Bv] * wr2);                        \
          v2f ti = pfma(Zi0[Bv], wr2,  Zr0[Bv] * wi2);                        \
          Zr0[Bv] = Zr0[A] - tr;  Zi0[Bv] = Zi0[A] - ti;                      \
          Zr0[A]  = Zr0[A] + tr;  Zi0[A]  = Zi0[A] + ti; }                    \
        { v2f tr = pfma(Zi1[Bv], nwi2, Zr1[Bv] * wr2);                        \
          v2f ti = pfma(Zi1[Bv], wr2,  Zr1[Bv] * wi2);                        \
          Zr1[Bv] = Zr1[A] - tr;  Zi1[Bv] = Zi1[A] - ti;                      \
          Zr1[A]  = Zr1[A] + tr;  Zi1[A]  = Zi1[A] + ti; }                    \
    }
    PBFLY2(0, 1, T4r, T4i)
    PBFLY2(2, 3, T4r, T4i)
    PBFLY2(0, 2, T2r, T2i)
    PBFLY2(1, 3, T2i, -T2r)

    // ---- final stage d=256 (both FFTs) ----
    float zrA[8], ziA[8], zrB[8], ziB[8];
    #pragma unroll
    for (int m = 0; m < 4; ++m) {
        const float Wr = (m == 0) ? T1r : (m == 1) ? A1r : (m == 2) ? A2r : A3r;
        const float Wi = (m == 0) ? T1i : (m == 1) ? A1i : (m == 2) ? A2i : A3i;
        { float tr = Zr0[m].y * Wr - Zi0[m].y * Wi;
          float ti = Zr0[m].y * Wi + Zi0[m].y * Wr;
          zrA[m]     = Zr0[m].x + tr;  ziA[m]     = Zi0[m].x + ti;
          zrA[m + 4] = Zr0[m].x - tr;  ziA[m + 4] = Zi0[m].x - ti; }
        { float tr = Zr1[m].y * Wr - Zi1[m].y * Wi;
          float ti = Zr1[m].y * Wi + Zi1[m].y * Wr;
          zrB[m]     = Zr1[m].x + tr;  ziB[m]     = Zi1[m].x + ti;
          zrB[m + 4] = Zr1[m].x - tr;  ziB[m + 4] = Zi1[m].x - ti; }
    }

    // ---- unpack 2x2 real spectra + power + energy ----
    v2f* PA = psA[w];
    v2f* PB = psB[w];
    const float inv = 1.0f / (4.0f * (float)NFFT);
    v2f eA = mk2(0.0f, 0.0f), eB = mk2(0.0f, 0.0f);
    const int ml = (64 - lane) & 63;
    #pragma unroll
    for (int r = 0; r < 4; ++r) {
        float mrA = __shfl(zrA[7 - r], ml), miA = __shfl(ziA[7 - r], ml);
        float mrB = __shfl(zrB[7 - r], ml), miB = __shfl(ziB[7 - r], ml);
        if (lane == 0) {
            mrA = zrA[(8 - r) & 7]; miA = ziA[(8 - r) & 7];
            mrB = zrB[(8 - r) & 7]; miB = ziB[(8 - r) & 7];
        }
        { float ar = zrA[r] + mrA, ai = ziA[r] - miA;
          float br = ziA[r] + miA, bi = zrA[r] - mrA;
          v2f p = mk2((ar * ar + ai * ai) * inv, (br * br + bi * bi) * inv);
          PA[64 * r + lane] = p;  eA += p; }
        { float ar = zrB[r] + mrB, ai = ziB[r] - miB;
          float br = ziB[r] + miB, bi = zrB[r] - mrB;
          v2f p = mk2((ar * ar + ai * ai) * inv, (br * br + bi * bi) * inv);
          PB[64 * r + lane] = p;  eB += p; }
    }
    if (lane == 0) {
        v2f pA = mk2(4.0f * zrA[4] * zrA[4] * inv, 4.0f * ziA[4] * ziA[4] * inv);
        v2f pB = mk2(4.0f * zrB[4] * zrB[4] * inv, 4.0f * ziB[4] * ziB[4] * inv);
        PA[256] = pA;  eA += pA;
        PB[256] = pB;  eB += pB;
    }
#define ERED(E)                                                               \
    E = E + mk2(fdpp<DPP_X1>(E.x),  fdpp<DPP_X1>(E.y));                       \
    E = E + mk2(fdpp<DPP_X2>(E.x),  fdpp<DPP_X2>(E.y));                       \
    E = E + mk2(fswz<SWZ_X4>(E.x),  fswz<SWZ_X4>(E.y));                       \
    E = E + mk2(fdpp<DPP_X8>(E.x),  fdpp<DPP_X8>(E.y));                       \
    E = E + mk2(fswz<SWZ_X16>(E.x), fswz<SWZ_X16>(E.y));                      \
    { uv2 rx = pl32(E.x), ry = pl32(E.y);                                     \
      E = mk2(__builtin_bit_cast(float, rx[0]) + __builtin_bit_cast(float, rx[1]), \
              __builtin_bit_cast(float, ry[0]) + __builtin_bit_cast(float, ry[1])); }
    ERED(eA)
    ERED(eB)
    __builtin_amdgcn_wave_barrier();

    // ---- mel filterbank: lanes 0..26 -> pair0 (packed), 32..58 -> pair1 ----
    const int  j  = lane & 31;
    const bool hi = lane >= 32;
    {
        const v2f* P = hi ? PB : PA;
        v2f fu = mk2(0, 0), fs = mk2(0, 0), fu2 = mk2(0, 0), fs2 = mk2(0, 0);
        if (j <= NFILT) {
            int bA = binsS[j], bZ = binsS[j + 1];
            int i = bA;
            for (; i + 1 < bZ; i += 2) {
                v2f p = P[i], p2 = P[i + 1];
                float c0 = (float)(i - bA), c1 = (float)(i + 1 - bA);
                fs  += p;   fu  = pfma(p,  mk2(c0, c0), fu);
                fs2 += p2;  fu2 = pfma(p2, mk2(c1, c1), fu2);
            }
            if (i < bZ) {
                v2f p = P[i];
                float c0 = (float)(i - bA);
                fs += p;  fu = pfma(p, mk2(c0, c0), fu);
            }
            fs += fs2;  fu += fu2;
            float iw = (bZ > bA) ? 1.0f / (float)(bZ - bA) : 0.0f;
            fu = fu * mk2(iw, iw);
        }
        v2f down = fs - fu;
        v2f dn = mk2(__shfl(down.x, lane + 1), __shfl(down.y, lane + 1));
        if (j < NFILT) {
            v2f ft = fu + dn;
            v2f fv = mk2(__logf(ft.x + EPSF), __logf(ft.y + EPSF));
            if (hi) featBs[w][j] = fv; else featAs[w][j] = fv;
        }
    }
    __builtin_amdgcn_wave_barrier();

    // ---- DCT (lifter pre-folded) + mask + store (4 frames) ----
    if (j < NUMCEP) {
        const v2f* ft = hi ? featBs[w] : featAs[w];
        v2f a0 = mk2(0, 0), a1 = mk2(0, 0);
        #pragma unroll
        for (int jj = 0; jj < NFILT; jj += 2) {
            float c0 = dctS[j * NFILT + jj], c1 = dctS[j * NFILT + jj + 1];
            a0 = pfma(ft[jj],     mk2(c0, c0), a0);
            a1 = pfma(ft[jj + 1], mk2(c1, c1), a1);
        }
        v2f val = a0 + a1;
        if (j == 0) {
            v2f E = hi ? eB : eA;
            val = mk2(__logf(E.x + EPSF), __logf(E.y + EPSF));
        }
        const int fb = f0 + (hi ? 2 : 0);
        long o0 = ((long)b * NFRAMES + fb) * NUMCEP + j;
        if (fb < NFRAMES)     out[o0]          = (fb     >= nf) ? 0.0f : val.x;
        if (fb + 1 < NFRAMES) out[o0 + NUMCEP] = (fb + 1 >= nf) ? 0.0f : val.y;
    }
}

extern "C" void kernel_launch(void* const* d_in, const int* in_sizes, int n_in,
                              void* d_out, int out_size, void* d_ws, size_t ws_size,
                              hipStream_t stream) {
    const float* sig     = (const float*)d_in[0];
    const int*   lengths = (const int*)d_in[1];
    float* out = (float*)d_out;

    mfcc_setup_kernel<<<1, 64, 0, stream>>>(lengths, d_ws,
                                            out + (size_t)BATCH * NFRAMES * NUMCEP);

    const int total_groups = BATCH * NGRP;       // 32000
    mfcc_kernel<<<total_groups / 4, 256, 0, stream>>>(sig, lengths, d_ws, out);
}